// Round 1
// baseline (221.129 us; speedup 1.0000x reference)
//
#include <hip/hip_runtime.h>
#include <math.h>

#define NSAMP 256000
#define NFRAMES 500
#define NBANKS 64
#define NBATCH 4
#define NFREQ 128001            // NSAMP/2 + 1
#define SRATE 22050.0f

typedef float2 cplx;

__device__ __forceinline__ cplx cmul(cplx a, cplx b) {
    return make_float2(a.x * b.x - a.y * b.y, a.x * b.y + a.y * b.x);
}
__device__ __forceinline__ cplx cadd(cplx a, cplx b) { return make_float2(a.x + b.x, a.y + b.y); }
__device__ __forceinline__ cplx csub(cplx a, cplx b) { return make_float2(a.x - b.x, a.y - b.y); }

// ---------------------------------------------------------------------------
// 1) per-frame mean weights (exact replica of the linspace/floor/scatter math)
// ---------------------------------------------------------------------------
__global__ __launch_bounds__(256) void kw_weights(float* __restrict__ wfr) {
    __shared__ float red[256];
    const int f = blockIdx.x;          // 0..NFRAMES-1
    const int tid = threadIdx.x;
    const double step = (double)(NFRAMES - 1) / (double)(NSAMP - 1);
    // only samples with pos in [f-1, f+1] can contribute
    int i0 = (int)((double)(f - 1) / step) - 4; if (i0 < 0) i0 = 0;
    int i1 = (int)((double)(f + 1) / step) + 4; if (i1 > NSAMP - 1) i1 = NSAMP - 1;
    float acc = 0.f;
    for (int i = i0 + tid; i <= i1; i += 256) {
        double pos = (double)i * step;
        int lo = (int)floor(pos);
        if (lo > NFRAMES - 2) lo = NFRAMES - 2;
        double frac = pos - (double)lo;
        if (lo == f)     acc += (float)(1.0 - frac);
        if (lo + 1 == f) acc += (float)frac;
    }
    red[tid] = acc;
    __syncthreads();
    for (int off = 128; off > 0; off >>= 1) {
        if (tid < off) red[tid] += red[tid + off];
        __syncthreads();
    }
    if (tid == 0) wfr[f] = red[0] / (float)NSAMP;
}

// ---------------------------------------------------------------------------
// 2) mean_mag[b][k] = sum_f fm[b][f][k] * wfr[f]   (single 256-thread block)
// ---------------------------------------------------------------------------
__global__ __launch_bounds__(256) void kw_meanmag(const float* __restrict__ fm,
                                                  const float* __restrict__ wfr,
                                                  float* __restrict__ mm) {
    const int t = threadIdx.x;         // b*64 + k
    const int b = t >> 6, k = t & 63;
    const float* p = fm + b * (NFRAMES * NBANKS) + k;
    float acc = 0.f;
    for (int f = 0; f < NFRAMES; ++f) acc += p[f * NBANKS] * wfr[f];
    mm[t] = acc;
}

// ---------------------------------------------------------------------------
// 3) response[b][k] = (sum_j w_j * mm_bj) / (sum_j w_j + 1e-7)
// ---------------------------------------------------------------------------
__global__ __launch_bounds__(256) void kw_resp(const float* __restrict__ mm,
                                               float* __restrict__ resp) {
    __shared__ float logff[NBANKS];
    __shared__ float mms[NBANKS];
    const int b = blockIdx.y;
    const int tid = threadIdx.x;
    if (tid < NBANKS) {
        double a = log10(20.0);
        double bb = log10((double)SRATE / 2.0);
        double e = a + (bb - a) * (double)tid / (double)(NBANKS - 1);
        float ff = (float)pow(10.0, e);
        logff[tid] = logf(ff + 1e-7f);
        mms[tid] = mm[b * NBANKS + tid];
    }
    __syncthreads();
    const int k = blockIdx.x * 256 + tid;
    if (k >= NFREQ) return;
    float freq = (float)k * (SRATE / (float)NSAMP);
    float lf = logf(freq + 1e-7f);
    float wsum = 0.f, wm = 0.f;
#pragma unroll
    for (int j = 0; j < NBANKS; ++j) {
        float d = lf - logff[j];
        float e = __expf(-2.0f * d * d);
        wsum += e;
        wm += e * mms[j];
    }
    resp[b * NFREQ + k] = wm / (wsum + 1e-7f);
}

// ---------------------------------------------------------------------------
// 4) pack real -> complex
// ---------------------------------------------------------------------------
__global__ __launch_bounds__(256) void kw_pack(const float* __restrict__ x,
                                               cplx* __restrict__ A) {
    int t = blockIdx.x * 256 + threadIdx.x;
    if (t < NBATCH * NSAMP) A[t] = make_float2(x[t], 0.f);
}

// ---------------------------------------------------------------------------
// 5) Stockham DIF stage, radix R. (n,s): m=n/R
//    in : x[q + s*(p + m*r)]      (q<s, p<m, r<R)
//    out: y[q + s*(R*p + u)] = (sum_r a_r w_R^{dir*u*r}) * e^{dir*(-2pi i) p u / n}
// ---------------------------------------------------------------------------
template <int R, bool INV>
__global__ __launch_bounds__(256) void kw_stage(const cplx* __restrict__ x,
                                                cplx* __restrict__ y,
                                                int n, int s) {
    const int per_batch = NSAMP / R;
    int t = blockIdx.x * 256 + threadIdx.x;
    if (t >= NBATCH * per_batch) return;
    const int b = t / per_batch;
    const int r = t - b * per_batch;
    const int q = r % s;
    const int p = r / s;
    const int m = n / R;
    const cplx* xb = x + b * NSAMP;
    cplx* yb = y + b * NSAMP;

    cplx a[R];
#pragma unroll
    for (int i = 0; i < R; ++i) a[i] = xb[q + s * (p + m * i)];

    cplx bb[R];
    if constexpr (R == 2) {
        bb[0] = cadd(a[0], a[1]);
        bb[1] = csub(a[0], a[1]);
    } else if constexpr (R == 4) {
        cplx t0 = cadd(a[0], a[2]);
        cplx t1 = csub(a[0], a[2]);
        cplx t2 = cadd(a[1], a[3]);
        cplx t3 = csub(a[1], a[3]);
        bb[0] = cadd(t0, t2);
        bb[2] = csub(t0, t2);
        if constexpr (!INV) {  // * (-i) t3
            bb[1] = make_float2(t1.x + t3.y, t1.y - t3.x);
            bb[3] = make_float2(t1.x - t3.y, t1.y + t3.x);
        } else {               // * (+i) t3
            bb[1] = make_float2(t1.x - t3.y, t1.y + t3.x);
            bb[3] = make_float2(t1.x + t3.y, t1.y - t3.x);
        }
    } else {  // R == 5
        const float c1 = 0.30901699437494742f, s1 = 0.95105651629515357f;
        const float c2 = -0.80901699437494745f, s2 = 0.58778525229247312f;
        const float sg = INV ? 1.0f : -1.0f;
        cplx W[5];
        W[0] = make_float2(1.f, 0.f);
        W[1] = make_float2(c1, sg * s1);
        W[2] = make_float2(c2, sg * s2);
        W[3] = make_float2(c2, -sg * s2);
        W[4] = make_float2(c1, -sg * s1);
#pragma unroll
        for (int u = 0; u < 5; ++u) {
            cplx acc = a[0];
            int idx = 0;
#pragma unroll
            for (int rr = 1; rr < 5; ++rr) {
                idx += u;
                if (idx >= 5) idx -= 5;
                acc = cadd(acc, cmul(a[rr], W[idx]));
            }
            bb[u] = acc;
        }
    }

    const float tw = (INV ? 2.0f : -2.0f) * 3.14159265358979323846f / (float)n;
#pragma unroll
    for (int u = 0; u < R; ++u) {
        cplx v = bb[u];
        if (u > 0) {
            float ang = tw * (float)(p * u);
            float sn, cs;
            sincosf(ang, &sn, &cs);
            v = make_float2(v.x * cs - v.y * sn, v.x * sn + v.y * cs);
        }
        yb[q + s * (R * p + u)] = v;
    }
}

// ---------------------------------------------------------------------------
// 6) pointwise: X[k] *= resp[b][min(k, N-k)] / N
// ---------------------------------------------------------------------------
__global__ __launch_bounds__(256) void kw_point(cplx* __restrict__ X,
                                                const float* __restrict__ resp) {
    int t = blockIdx.x * 256 + threadIdx.x;
    if (t >= NBATCH * NSAMP) return;
    int b = t / NSAMP;
    int k = t - b * NSAMP;
    int idx = (k <= NSAMP / 2) ? k : (NSAMP - k);
    float h = resp[b * NFREQ + idx] * (1.0f / (float)NSAMP);
    cplx v = X[t];
    X[t] = make_float2(v.x * h, v.y * h);
}

// ---------------------------------------------------------------------------
// 7) extract real part
// ---------------------------------------------------------------------------
__global__ __launch_bounds__(256) void kw_extract(const cplx* __restrict__ A,
                                                  float* __restrict__ out) {
    int t = blockIdx.x * 256 + threadIdx.x;
    if (t < NBATCH * NSAMP) out[t] = A[t].x;
}

// ---------------------------------------------------------------------------
extern "C" void kernel_launch(void* const* d_in, const int* in_sizes, int n_in,
                              void* d_out, int out_size, void* d_ws, size_t ws_size,
                              hipStream_t stream) {
    const float* fm = (const float*)d_in[0];     // (4,500,64)
    const float* noise = (const float*)d_in[1];  // (4,256000)
    float* out = (float*)d_out;

    char* ws = (char*)d_ws;
    cplx* A = (cplx*)ws;                          //  8,192,000 B
    cplx* Bb = (cplx*)(ws + 8192000);             //  8,192,000 B
    float* wfr = (float*)(ws + 16384000);         //      2,000 B
    float* mm = (float*)(ws + 16386048);          //      1,024 B
    float* resp = (float*)(ws + 16387072);        //  2,048,016 B  (total ~18.4 MB)

    kw_weights<<<NFRAMES, 256, 0, stream>>>(wfr);
    kw_meanmag<<<1, 256, 0, stream>>>(fm, wfr, mm);
    kw_resp<<<dim3((NFREQ + 255) / 256, NBATCH), 256, 0, stream>>>(mm, resp);
    kw_pack<<<(NBATCH * NSAMP + 255) / 256, 256, 0, stream>>>(noise, A);

    const int rad[9] = {5, 5, 5, 4, 4, 4, 4, 4, 2};

    // forward FFT
    cplx* src = A;
    cplx* dst = Bb;
    int n = NSAMP, s = 1;
    for (int i = 0; i < 9; ++i) {
        int R = rad[i];
        int threads = NBATCH * NSAMP / R;
        int blocks = (threads + 255) / 256;
        if (R == 5)      kw_stage<5, false><<<blocks, 256, 0, stream>>>(src, dst, n, s);
        else if (R == 4) kw_stage<4, false><<<blocks, 256, 0, stream>>>(src, dst, n, s);
        else             kw_stage<2, false><<<blocks, 256, 0, stream>>>(src, dst, n, s);
        n /= R; s *= R;
        cplx* tmp = src; src = dst; dst = tmp;
    }
    // src now holds the natural-order spectrum

    kw_point<<<(NBATCH * NSAMP + 255) / 256, 256, 0, stream>>>(src, resp);

    // inverse FFT
    n = NSAMP; s = 1;
    for (int i = 0; i < 9; ++i) {
        int R = rad[i];
        int threads = NBATCH * NSAMP / R;
        int blocks = (threads + 255) / 256;
        if (R == 5)      kw_stage<5, true><<<blocks, 256, 0, stream>>>(src, dst, n, s);
        else if (R == 4) kw_stage<4, true><<<blocks, 256, 0, stream>>>(src, dst, n, s);
        else             kw_stage<2, true><<<blocks, 256, 0, stream>>>(src, dst, n, s);
        n /= R; s *= R;
        cplx* tmp = src; src = dst; dst = tmp;
    }

    kw_extract<<<(NBATCH * NSAMP + 255) / 256, 256, 0, stream>>>(src, out);
}

// Round 2
// 115.648 us; speedup vs baseline: 1.9121x; 1.9121x over previous
//
#include <hip/hip_runtime.h>
#include <math.h>

#define NS 256000
#define N1 512            // FFT length over n1 (radix 8,8,8)
#define N2 500            // FFT length over n2 (radices 5,5,5,4)
#define NB 4
#define PI_F 3.14159265358979323846f

typedef float2 cplx;

__device__ __forceinline__ cplx cadd(cplx a, cplx b){ return make_float2(a.x+b.x, a.y+b.y); }
__device__ __forceinline__ cplx csub(cplx a, cplx b){ return make_float2(a.x-b.x, a.y-b.y); }
__device__ __forceinline__ cplx cmul(cplx a, cplx b){ return make_float2(a.x*b.x-a.y*b.y, a.x*b.y+a.y*b.x); }
// a * conj(b)
__device__ __forceinline__ cplx cmulc(cplx a, cplx b){ return make_float2(a.x*b.x+a.y*b.y, a.y*b.x-a.x*b.y); }
__device__ __forceinline__ cplx crot(cplx v, float ang){
    float sn, cs; sincosf(ang, &sn, &cs);
    return make_float2(v.x*cs - v.y*sn, v.x*sn + v.y*cs);
}
// LDS index with skew: element e, column c (8 columns), stride 9 + e>>6 skew
__device__ __forceinline__ int LX(int e, int c){ return e*9 + (e>>6) + c; }

template<bool INV>
__device__ __forceinline__ void dft4(const cplx* a, cplx* b){
    cplx t0=cadd(a[0],a[2]), t1=csub(a[0],a[2]), t2=cadd(a[1],a[3]), t3=csub(a[1],a[3]);
    b[0]=cadd(t0,t2); b[2]=csub(t0,t2);
    if(!INV){ b[1]=make_float2(t1.x+t3.y, t1.y-t3.x); b[3]=make_float2(t1.x-t3.y, t1.y+t3.x); }
    else    { b[1]=make_float2(t1.x-t3.y, t1.y+t3.x); b[3]=make_float2(t1.x+t3.y, t1.y-t3.x); }
}

template<bool INV>
__device__ __forceinline__ void dft8(const cplx* a, cplx* b){
    cplx ev[4]={a[0],a[2],a[4],a[6]}, od[4]={a[1],a[3],a[5],a[7]};
    cplx C[4], D[4];
    dft4<INV>(ev, C); dft4<INV>(od, D);
    const float s = 0.70710678118654752f;
    const float sg = INV ? 1.f : -1.f;
    cplx d1 = cmul(D[1], make_float2( s, sg*s));
    cplx d2 = cmul(D[2], make_float2(0.f, sg ));
    cplx d3 = cmul(D[3], make_float2(-s, sg*s));
    b[0]=cadd(C[0],D[0]); b[4]=csub(C[0],D[0]);
    b[1]=cadd(C[1],d1);   b[5]=csub(C[1],d1);
    b[2]=cadd(C[2],d2);   b[6]=csub(C[2],d2);
    b[3]=cadd(C[3],d3);   b[7]=csub(C[3],d3);
}

template<bool INV>
__device__ __forceinline__ void dft5(const cplx* a, cplx* b){
    const float c1=0.30901699437494742f, s1=0.95105651629515357f;
    const float c2=-0.80901699437494745f, s2=0.58778525229247312f;
    const float sg = INV ? 1.f : -1.f;
    cplx W[5];
    W[0]=make_float2(1.f,0.f);
    W[1]=make_float2(c1, sg*s1); W[2]=make_float2(c2, sg*s2);
    W[3]=make_float2(c2,-sg*s2); W[4]=make_float2(c1,-sg*s1);
#pragma unroll
    for(int u=0;u<5;++u){
        cplx acc = a[0];
        int idx = 0;
#pragma unroll
        for(int r=1;r<5;++r){
            idx += u; if(idx >= 5) idx -= 5;
            acc = cadd(acc, cmul(a[r], W[idx]));
        }
        b[u] = acc;
    }
}

// In-place DIF (fwd: DFT then twiddle-after) / DIT (inv: twiddle-before then DFT).
// Stage (L, R): m = L/R; butterfly beta: blk = beta/m, j = beta%m, base = blk*L + j,
// elements {base + m*t}. Twiddle = tab[tmul*j*t] (fwd) or conj (inv). NN total len.
template<int R, bool INV, int NN>
__device__ void ip_stage(cplx* lds, const cplx* tab, int tmul, int L, int fi, int jl){
    const int m = L / R;
    const int nb = NN / R;
    for(int beta = jl; beta < nb; beta += 64){
        int blk = beta / m;
        int j = beta - blk*m;
        int base = blk*L + j;
        cplx a[R];
#pragma unroll
        for(int t=0;t<R;++t) a[t] = lds[LX(base + m*t, fi)];
        if(INV && j){
#pragma unroll
            for(int t=1;t<R;++t) a[t] = cmulc(a[t], tab[tmul*j*t]);
        }
        cplx b[R];
        if constexpr (R==4) dft4<INV>(a,b);
        else if constexpr (R==5) dft5<INV>(a,b);
        else dft8<INV>(a,b);
        if(!INV && j){
#pragma unroll
            for(int t=1;t<R;++t) b[t] = cmul(b[t], tab[tmul*j*t]);
        }
#pragma unroll
        for(int t=0;t<R;++t) lds[LX(base + m*t, fi)] = b[t];
    }
}

__device__ __forceinline__ void build_tab(cplx* tab, int n, int tid, int nthr){
    for(int i = tid; i < n; i += nthr){
        float ang = -2.f*PI_F*(float)i/(float)n;
        float sn, cs; sincosf(ang, &sn, &cs);
        tab[i] = make_float2(cs, sn);
    }
}

// octal digit reversal of 9 bits (512 = 8^3): DIF output position of k
__device__ __forceinline__ int rev8_3(int k){
    return ((k & 7) << 6) | (k & 0x38) | (k >> 6);
}

// ---------------------------------------------------------------------------
// T1: exact closed-form frame-mean weights + mean_mag.  grid=(4), 256 thr.
//   step = 499/255999;  A(f) = sum_{i=i0(f)}^{i1(f)-1} (pos_i - f)  (exact int64)
//   w[f] = (cnt_f - A(f)) + A(f-1), f<499;  w[499] = A(498) + 1
// ---------------------------------------------------------------------------
__global__ __launch_bounds__(256) void kT1(const float* __restrict__ fm,
                                           float* __restrict__ mm){
    __shared__ float Aarr[500];
    __shared__ float wfr[500];
    __shared__ float part[4*64];
    const int b = blockIdx.x, tid = threadIdx.x;
    for(int f = tid; f < 500; f += 256){
        long long i0 = ((long long)f*255999LL + 498LL)/499LL;
        long long i1 = ((long long)(f+1)*255999LL + 498LL)/499LL;
        long long cnt = i1 - i0;
        long long sumi = (i0 + i1 - 1)*cnt/2;
        long long num = 499LL*sumi - cnt*(long long)f*255999LL;
        Aarr[f] = (float)((double)num / 255999.0);
    }
    __syncthreads();
    for(int f = tid; f < 500; f += 256){
        long long i0 = ((long long)f*255999LL + 498LL)/499LL;
        long long i1 = ((long long)(f+1)*255999LL + 498LL)/499LL;
        double w;
        if(f < 499) w = (double)(i1 - i0) - (double)Aarr[f] + (f > 0 ? (double)Aarr[f-1] : 0.0);
        else        w = (double)Aarr[498] + 1.0;
        wfr[f] = (float)(w / (double)NS);
    }
    __syncthreads();
    const int k = tid & 63, seg = tid >> 6;
    float acc = 0.f;
    for(int f = seg*125; f < seg*125 + 125; ++f)
        acc += wfr[f] * fm[(b*500 + f)*64 + k];
    part[seg*64 + k] = acc;
    __syncthreads();
    if(tid < 64) mm[b*64 + tid] = part[tid] + part[64+tid] + part[128+tid] + part[192+tid];
}

// ---------------------------------------------------------------------------
// T2: filter response, written directly in kB's DIF position order.
// grid=(512) over k1; computes exps once, reused across the 4 batches.
// position p <-> k2:  p = 100t1+20t2+4t3+t4,  k2 = t1+5t2+25t3+125t4
// ---------------------------------------------------------------------------
__global__ __launch_bounds__(256) void kT2(const float* __restrict__ mm,
                                           float* __restrict__ resp2){
    __shared__ float logff[64];
    __shared__ float mmS[4][64];
    const int k1 = blockIdx.x, tid = threadIdx.x;
    if(tid < 64){
        double a = log10(20.0), bb = log10(11025.0);
        double e = a + (bb - a)*(double)tid/63.0;
        float ff = (float)pow(10.0, e);
        logff[tid] = logf(ff + 1e-7f);
    }
    if(tid < 256){ mmS[tid>>6][tid&63] = mm[tid]; }
    __syncthreads();
    for(int p = tid; p < N2; p += 256){
        int t1 = p/100; int r = p - 100*t1;
        int t2 = r/20;  r -= 20*t2;
        int t3 = r>>2;  int t4 = r & 3;
        int k2 = t1 + 5*t2 + 25*t3 + 125*t4;
        int kf = k1 + N1*k2;
        int kk = min(kf, NS - kf);
        float lf = logf((float)kk*(22050.f/(float)NS) + 1e-7f);
        float wsum=0.f, w0=0.f, w1=0.f, w2=0.f, w3=0.f;
#pragma unroll
        for(int j=0;j<64;++j){
            float d = lf - logff[j];
            float e = __expf(-2.f*d*d);
            wsum += e;
            w0 += e*mmS[0][j]; w1 += e*mmS[1][j]; w2 += e*mmS[2][j]; w3 += e*mmS[3][j];
        }
        float inv = 1.f/(wsum + 1e-7f);
        resp2[(0*N1 + k1)*N2 + p] = w0*inv;
        resp2[(1*N1 + k1)*N2 + p] = w1*inv;
        resp2[(2*N1 + k1)*N2 + p] = w2*inv;
        resp2[(3*N1 + k1)*N2 + p] = w3*inv;
    }
}

// ---------------------------------------------------------------------------
// kA: forward 512-point FFT over n1 for 8 n2-columns, + twiddle e^{-2pi n2 k1/NS}
// grid (63,4), 512 threads.  Y[(b*500+n2)*512 + k1], natural k1 order.
// ---------------------------------------------------------------------------
__global__ __launch_bounds__(512) void kA(const float* __restrict__ x,
                                          cplx* __restrict__ Y){
    __shared__ cplx U[512*9 + 8];
    __shared__ cplx tab[512];
    const int tile = blockIdx.x, b = blockIdx.y, tid = threadIdx.x;
    const int n2base = tile*8;
    build_tab(tab, 512, tid, 512);
    // load real input: x[b][500*n1 + n2]
    for(int i = tid; i < N1*8; i += 512){
        int n1 = i >> 3, f = i & 7;
        int n2 = n2base + f;
        float v = (n2 < N2) ? x[b*NS + n1*N2 + n2] : 0.f;
        U[LX(n1, f)] = make_float2(v, 0.f);
    }
    __syncthreads();
    const int fi = tid & 7, jl = tid >> 3;
    ip_stage<8,false,N1>(U, tab,  1, 512, fi, jl); __syncthreads();
    ip_stage<8,false,N1>(U, tab,  8,  64, fi, jl); __syncthreads();
    ip_stage<8,false,N1>(U, tab, 64,   8, fi, jl); __syncthreads();
    // twiddle + store (DIF left k1 at position rev8_3(k1))
    const int sub = tid >> 6, k1c = tid & 63;
    const int n2 = n2base + sub;
    if(n2 < N2){
        const float tw = -2.f*PI_F/(float)NS;
        cplx* dst = Y + (b*N2 + n2)*N1;
        for(int k1 = k1c; k1 < N1; k1 += 64){
            cplx v = U[LX(rev8_3(k1), sub)];
            v = crot(v, tw*(float)(n2*k1));
            dst[k1] = v;
        }
    }
}

// ---------------------------------------------------------------------------
// kB: per k1-column tile (8 cols): fwd 500-FFT over n2, apply H/NS (position
// order), inv 500-FFT, inverse twiddle e^{+2pi n2 k1/NS}; in-place on Y.
// grid (64,4), 512 threads.
// ---------------------------------------------------------------------------
__global__ __launch_bounds__(512) void kB(cplx* __restrict__ Y,
                                          const float* __restrict__ resp2){
    __shared__ cplx U[500*9 + 8];
    __shared__ cplx tab[500];
    const int k0 = blockIdx.x*8, b = blockIdx.y, tid = threadIdx.x;
    build_tab(tab, 500, tid, 512);
    const int fi = tid & 7, jl = tid >> 3;
    // load columns k0+fi
    for(int n2 = tid >> 3; n2 < N2; n2 += 64)
        U[LX(n2, fi)] = Y[(b*N2 + n2)*N1 + k0 + fi];
    __syncthreads();
    ip_stage<5,false,N2>(U, tab,   1, 500, fi, jl); __syncthreads();
    ip_stage<5,false,N2>(U, tab,   5, 100, fi, jl); __syncthreads();
    ip_stage<5,false,N2>(U, tab,  25,  20, fi, jl); __syncthreads();
    ip_stage<4,false,N2>(U, tab, 125,   4, fi, jl); __syncthreads();
    // H multiply (resp2 already in position order)
    {
        const int sub = tid >> 6, pc = tid & 63;
        const float invN = 1.f/(float)NS;
        const float* rp = resp2 + (b*N1 + k0 + sub)*N2;
        for(int p = pc; p < N2; p += 64){
            float h = rp[p]*invN;
            cplx v = U[LX(p, sub)];
            U[LX(p, sub)] = make_float2(v.x*h, v.y*h);
        }
    }
    __syncthreads();
    ip_stage<4,true,N2>(U, tab, 125,   4, fi, jl); __syncthreads();
    ip_stage<5,true,N2>(U, tab,  25,  20, fi, jl); __syncthreads();
    ip_stage<5,true,N2>(U, tab,   5, 100, fi, jl); __syncthreads();
    ip_stage<5,true,N2>(U, tab,   1, 500, fi, jl); __syncthreads();
    // inverse twiddle + store back
    const int k1 = k0 + fi;
    const float tw = 2.f*PI_F/(float)NS;
    for(int n2 = tid >> 3; n2 < N2; n2 += 64){
        cplx v = U[LX(n2, fi)];
        v = crot(v, tw*(float)(n2*k1));
        Y[(b*N2 + n2)*N1 + k1] = v;
    }
}

// ---------------------------------------------------------------------------
// kC: inverse 512-point FFT over k1 per n2-column, real output.
// grid (63,4), 512 threads.  out[b][500*n1 + n2].
// ---------------------------------------------------------------------------
__global__ __launch_bounds__(512) void kC(const cplx* __restrict__ Y,
                                          float* __restrict__ out){
    __shared__ cplx U[512*9 + 8];
    __shared__ cplx tab[512];
    const int tile = blockIdx.x, b = blockIdx.y, tid = threadIdx.x;
    const int n2base = tile*8;
    build_tab(tab, 512, tid, 512);
    // load natural k1 into digit-reversed position (DIT input order)
    {
        const int sub = tid >> 6, k1c = tid & 63;
        const int n2 = n2base + sub;
        for(int k1 = k1c; k1 < N1; k1 += 64){
            cplx v = make_float2(0.f, 0.f);
            if(n2 < N2) v = Y[(b*N2 + n2)*N1 + k1];
            U[LX(rev8_3(k1), sub)] = v;
        }
    }
    __syncthreads();
    const int fi = tid & 7, jl = tid >> 3;
    ip_stage<8,true,N1>(U, tab, 64,   8, fi, jl); __syncthreads();
    ip_stage<8,true,N1>(U, tab,  8,  64, fi, jl); __syncthreads();
    ip_stage<8,true,N1>(U, tab,  1, 512, fi, jl); __syncthreads();
    const int n2 = n2base + fi;
    if(n2 < N2){
        for(int n1 = tid >> 3; n1 < N1; n1 += 64)
            out[b*NS + n1*N2 + n2] = U[LX(n1, fi)].x;
    }
}

// ---------------------------------------------------------------------------
extern "C" void kernel_launch(void* const* d_in, const int* in_sizes, int n_in,
                              void* d_out, int out_size, void* d_ws, size_t ws_size,
                              hipStream_t stream) {
    const float* fm = (const float*)d_in[0];     // (4,500,64)
    const float* noise = (const float*)d_in[1];  // (4,256000)
    float* out = (float*)d_out;

    char* ws = (char*)d_ws;
    cplx*  Y     = (cplx*)ws;                    //  8,192,000 B
    float* resp2 = (float*)(ws + 8192000);       //  4,096,000 B
    float* mm    = (float*)(ws + 12288000);      //      1,024 B

    kT1<<<4, 256, 0, stream>>>(fm, mm);
    kT2<<<512, 256, 0, stream>>>(mm, resp2);
    kA<<<dim3(63,4), 512, 0, stream>>>(noise, Y);
    kB<<<dim3(64,4), 512, 0, stream>>>(Y, resp2);
    kC<<<dim3(63,4), 512, 0, stream>>>(Y, out);
}

// Round 3
// 111.503 us; speedup vs baseline: 1.9832x; 1.0372x over previous
//
#include <hip/hip_runtime.h>
#include <math.h>

#define NS 256000
#define N1 512            // FFT over n1: radix 8,8,8
#define N2 500            // FFT over n2: radices 5,5,5,4
#define PI_F 3.14159265358979323846f

typedef float2 cplx;

__device__ __forceinline__ cplx cadd(cplx a, cplx b){ return make_float2(a.x+b.x, a.y+b.y); }
__device__ __forceinline__ cplx csub(cplx a, cplx b){ return make_float2(a.x-b.x, a.y-b.y); }
__device__ __forceinline__ cplx cmul(cplx a, cplx b){ return make_float2(a.x*b.x-a.y*b.y, a.x*b.y+a.y*b.x); }
__device__ __forceinline__ cplx cmulc(cplx a, cplx b){ return make_float2(a.x*b.x+a.y*b.y, a.y*b.x-a.x*b.y); }
__device__ __forceinline__ cplx crotf(cplx v, float ang){
    float sn = __sinf(ang), cs = __cosf(ang);
    return make_float2(v.x*cs - v.y*sn, v.x*sn + v.y*cs);
}
// padded LDS index: +1 word every 16 elements -> <=2-way bank aliasing
__device__ __forceinline__ int PX(int e){ return e + (e>>4); }
// octal digit reversal of 9 bits (involution)
__device__ __forceinline__ int rev8_3(int k){ return ((k&7)<<6) | (k&0x38) | (k>>6); }

#define U1PAD 545   // >= PX(511)+1 = 543, odd for column-phase bank spread
#define U2PAD 537   // >= PX(499)+1 = 531, odd

template<bool INV>
__device__ __forceinline__ void dft4(const cplx* a, cplx* b){
    cplx t0=cadd(a[0],a[2]), t1=csub(a[0],a[2]), t2=cadd(a[1],a[3]), t3=csub(a[1],a[3]);
    b[0]=cadd(t0,t2); b[2]=csub(t0,t2);
    if(!INV){ b[1]=make_float2(t1.x+t3.y, t1.y-t3.x); b[3]=make_float2(t1.x-t3.y, t1.y+t3.x); }
    else    { b[1]=make_float2(t1.x-t3.y, t1.y+t3.x); b[3]=make_float2(t1.x+t3.y, t1.y-t3.x); }
}

template<bool INV>
__device__ __forceinline__ void dft8(const cplx* a, cplx* b){
    cplx ev[4]={a[0],a[2],a[4],a[6]}, od[4]={a[1],a[3],a[5],a[7]};
    cplx C[4], D[4];
    dft4<INV>(ev, C); dft4<INV>(od, D);
    const float s = 0.70710678118654752f;
    const float sg = INV ? 1.f : -1.f;
    cplx d1 = cmul(D[1], make_float2( s, sg*s));
    cplx d2 = cmul(D[2], make_float2(0.f, sg ));
    cplx d3 = cmul(D[3], make_float2(-s, sg*s));
    b[0]=cadd(C[0],D[0]); b[4]=csub(C[0],D[0]);
    b[1]=cadd(C[1],d1);   b[5]=csub(C[1],d1);
    b[2]=cadd(C[2],d2);   b[6]=csub(C[2],d2);
    b[3]=cadd(C[3],d3);   b[7]=csub(C[3],d3);
}

template<bool INV>
__device__ __forceinline__ void dft5(const cplx* a, cplx* b){
    const float c1=0.30901699437494742f, s1=0.95105651629515357f;
    const float c2=-0.80901699437494745f, s2=0.58778525229247312f;
    const float sg = INV ? 1.f : -1.f;
    cplx W[5];
    W[0]=make_float2(1.f,0.f);
    W[1]=make_float2(c1, sg*s1); W[2]=make_float2(c2, sg*s2);
    W[3]=make_float2(c2,-sg*s2); W[4]=make_float2(c1,-sg*s1);
#pragma unroll
    for(int u=0;u<5;++u){
        cplx acc = a[0];
        int idx = 0;
#pragma unroll
        for(int r=1;r<5;++r){
            idx += u; if(idx >= 5) idx -= 5;
            acc = cadd(acc, cmul(a[r], W[idx]));
        }
        b[u] = acc;
    }
}

// One in-place Stockham-style stage on a wave-private LDS column.
// fwd (DIF): DFT then twiddle-after; inv (DIT): conj-twiddle-before then DFT.
// All shape params compile-time; tab[0]=(1,0) so j==0 multiply is exact identity.
template<int R, int L, int TMUL, bool INV, int NN>
__device__ __forceinline__ void wstage(cplx* Uw, const cplx* tab, int lane){
    constexpr int m = L / R;
    constexpr int nb = NN / R;
#pragma unroll
    for(int it = 0; it < (nb + 63) / 64; ++it){
        int beta = lane + it*64;
        if(beta < nb){
            int blk = beta / m;
            int j = beta - blk*m;
            int base = blk*L + j;
            cplx a[R];
#pragma unroll
            for(int t=0;t<R;++t) a[t] = Uw[PX(base + m*t)];
            if(INV){
#pragma unroll
                for(int t=1;t<R;++t) a[t] = cmulc(a[t], tab[TMUL*j*t]);
            }
            cplx bb[R];
            if constexpr (R==4) dft4<INV>(a,bb);
            else if constexpr (R==5) dft5<INV>(a,bb);
            else dft8<INV>(a,bb);
            if(!INV){
#pragma unroll
                for(int t=1;t<R;++t) bb[t] = cmul(bb[t], tab[TMUL*j*t]);
            }
#pragma unroll
            for(int t=0;t<R;++t) Uw[PX(base + m*t)] = bb[t];
        }
    }
}

template<int NTAB>
__device__ __forceinline__ void build_tab(cplx* tab, int tid){
    const float step = -2.f*PI_F/(float)NTAB;
    for(int i = tid; i < NTAB; i += 256){
        float a = step*(float)i;
        tab[i] = make_float2(__cosf(a), __sinf(a));
    }
}

// ---------------------------------------------------------------------------
// T1: closed-form frame-mean weights + mean_mag.  grid=(4), 256 thr.
// ---------------------------------------------------------------------------
__global__ __launch_bounds__(256) void kT1(const float* __restrict__ fm,
                                           float* __restrict__ mm){
    __shared__ float Aarr[500];
    __shared__ float wfr[500];
    __shared__ float part[4*64];
    const int b = blockIdx.x, tid = threadIdx.x;
    for(int f = tid; f < 500; f += 256){
        long long i0 = ((long long)f*255999LL + 498LL)/499LL;
        long long i1 = ((long long)(f+1)*255999LL + 498LL)/499LL;
        long long cnt = i1 - i0;
        long long sumi = (i0 + i1 - 1)*cnt/2;
        long long num = 499LL*sumi - cnt*(long long)f*255999LL;
        Aarr[f] = (float)((double)num / 255999.0);
    }
    __syncthreads();
    for(int f = tid; f < 500; f += 256){
        long long i0 = ((long long)f*255999LL + 498LL)/499LL;
        long long i1 = ((long long)(f+1)*255999LL + 498LL)/499LL;
        double w;
        if(f < 499) w = (double)(i1 - i0) - (double)Aarr[f] + (f > 0 ? (double)Aarr[f-1] : 0.0);
        else        w = (double)Aarr[498] + 1.0;
        wfr[f] = (float)(w / (double)NS);
    }
    __syncthreads();
    const int k = tid & 63, seg = tid >> 6;
    float acc = 0.f;
    for(int f = seg*125; f < seg*125 + 125; ++f)
        acc += wfr[f] * fm[(b*500 + f)*64 + k];
    part[seg*64 + k] = acc;
    __syncthreads();
    if(tid < 64) mm[b*64 + tid] = part[tid] + part[64+tid] + part[128+tid] + part[192+tid];
}

// ---------------------------------------------------------------------------
// T2: filter response in the 500-FFT DIF position order, indexed by true k1.
// grid=(512) over k1.
// ---------------------------------------------------------------------------
__global__ __launch_bounds__(256) void kT2(const float* __restrict__ mm,
                                           float* __restrict__ resp2){
    __shared__ float logff[64];
    __shared__ float mmS[4][64];
    const int k1 = blockIdx.x, tid = threadIdx.x;
    if(tid < 64){
        double a = log10(20.0), bb = log10(11025.0);
        double e = a + (bb - a)*(double)tid/63.0;
        float ff = (float)pow(10.0, e);
        logff[tid] = logf(ff + 1e-7f);
    }
    if(tid < 256){ mmS[tid>>6][tid&63] = mm[tid]; }
    __syncthreads();
    for(int p = tid; p < N2; p += 256){
        int t1 = p/100; int r = p - 100*t1;
        int t2 = r/20;  r -= 20*t2;
        int t3 = r>>2;  int t4 = r & 3;
        int k2 = t1 + 5*t2 + 25*t3 + 125*t4;
        int kf = k1 + N1*k2;
        int kk = min(kf, NS - kf);
        float lf = logf((float)kk*(22050.f/(float)NS) + 1e-7f);
        float wsum=0.f, w0=0.f, w1=0.f, w2=0.f, w3=0.f;
#pragma unroll
        for(int j=0;j<64;++j){
            float d = lf - logff[j];
            float e = __expf(-2.f*d*d);
            wsum += e;
            w0 += e*mmS[0][j]; w1 += e*mmS[1][j]; w2 += e*mmS[2][j]; w3 += e*mmS[3][j];
        }
        float inv = 1.f/(wsum + 1e-7f);
        resp2[(0*N1 + k1)*N2 + p] = w0*inv;
        resp2[(1*N1 + k1)*N2 + p] = w1*inv;
        resp2[(2*N1 + k1)*N2 + p] = w2*inv;
        resp2[(3*N1 + k1)*N2 + p] = w3*inv;
    }
}

// ---------------------------------------------------------------------------
// kA: wave-per-(b,n2) forward 512-FFT, + inter-pass twiddle, store in DIF
// position order (coalesced).  grid=(500), 256 thr (4 waves = 4 n2 columns).
// ---------------------------------------------------------------------------
__global__ __launch_bounds__(256) void kA(const float* __restrict__ x,
                                          cplx* __restrict__ Y){
    __shared__ cplx tab[512];
    __shared__ cplx U[4][U1PAD];
    const int tid = threadIdx.x, lane = tid & 63, w = tid >> 6;
    const int g = blockIdx.x;
    const int b = g / 125;
    const int n2base = (g - b*125) * 4;
    build_tab<512>(tab, tid);
    __syncthreads();
    // cooperative tiled load: 16 B segments over [n1][n2base..n2base+3]
    const float* xb = x + b*NS + n2base;
    for(int i = tid; i < 512*4; i += 256){
        int n1 = i >> 2, ws = i & 3;
        U[ws][PX(n1)] = make_float2(xb[n1*500 + ws], 0.f);
    }
    __syncthreads();
    cplx* Uw = U[w];
    wstage<8,512, 1,false,512>(Uw, tab, lane); __syncthreads();
    wstage<8, 64, 8,false,512>(Uw, tab, lane); __syncthreads();
    wstage<8,  8,64,false,512>(Uw, tab, lane); __syncthreads();
    // per-wave twiddle + coalesced position-order store
    const int n2 = n2base + w;
    cplx* yp = Y + (b*N2 + n2)*N1;
    const float tw = -2.f*PI_F/(float)NS;
#pragma unroll
    for(int t = 0; t < 8; ++t){
        int p = lane + 64*t;
        int k1 = rev8_3(p);
        cplx v = Uw[PX(p)];
        v = crotf(v, tw*(float)(n2*k1));
        yp[p] = v;
    }
}

// ---------------------------------------------------------------------------
// kB: wave-per-(b,p1) column: fwd 500-FFT, *H/NS, inv 500-FFT, inv twiddle.
// In-place on Y.  grid=(512), 256 thr (4 waves = 4 p1 columns).
// ---------------------------------------------------------------------------
__global__ __launch_bounds__(256) void kB(cplx* __restrict__ Y,
                                          const float* __restrict__ resp2){
    __shared__ cplx tab[500];
    __shared__ cplx U[4][U2PAD];
    const int tid = threadIdx.x, lane = tid & 63, w = tid >> 6;
    const int b = blockIdx.x >> 7;
    const int p1base = (blockIdx.x & 127) * 4;
    build_tab<500>(tab, tid);
    __syncthreads();
    // cooperative tiled load: 32 B segments over [n2][p1base..p1base+3]
    cplx* yb = Y + b*NS + p1base;
    for(int i = tid; i < 500*4; i += 256){
        int n2 = i >> 2, ws = i & 3;
        U[ws][PX(n2)] = yb[n2*N1 + ws];
    }
    __syncthreads();
    cplx* Uw = U[w];
    wstage<5,500,  1,false,500>(Uw, tab, lane); __syncthreads();
    wstage<5,100,  5,false,500>(Uw, tab, lane); __syncthreads();
    wstage<5, 20, 25,false,500>(Uw, tab, lane); __syncthreads();
    wstage<4,  4,125,false,500>(Uw, tab, lane); __syncthreads();
    // H multiply (resp2 in matching position order, keyed by true k1)
    {
        const int k1 = rev8_3(p1base + w);
        const float invN = 1.f/(float)NS;
        const float* rp = resp2 + (b*N1 + k1)*N2;
#pragma unroll
        for(int t = 0; t < 8; ++t){
            int p = lane + 64*t;
            if(p < 500){
                float h = rp[p]*invN;
                cplx v = Uw[PX(p)];
                Uw[PX(p)] = make_float2(v.x*h, v.y*h);
            }
        }
    }
    __syncthreads();
    wstage<4,  4,125,true,500>(Uw, tab, lane); __syncthreads();
    wstage<5, 20, 25,true,500>(Uw, tab, lane); __syncthreads();
    wstage<5,100,  5,true,500>(Uw, tab, lane); __syncthreads();
    wstage<5,500,  1,true,500>(Uw, tab, lane); __syncthreads();
    // cooperative store with fused inverse inter-pass twiddle
    const float tw = 2.f*PI_F/(float)NS;
    for(int i = tid; i < 500*4; i += 256){
        int n2 = i >> 2, ws = i & 3;
        int k1 = rev8_3(p1base + ws);
        cplx v = U[ws][PX(n2)];
        v = crotf(v, tw*(float)(n2*k1));
        yb[n2*N1 + ws] = v;
    }
}

// ---------------------------------------------------------------------------
// kC: wave-per-(b,n2) inverse 512-FFT (DIT consumes position order), real out.
// grid=(500), 256 thr.
// ---------------------------------------------------------------------------
__global__ __launch_bounds__(256) void kC(const cplx* __restrict__ Y,
                                          float* __restrict__ out){
    __shared__ cplx tab[512];
    __shared__ cplx U[4][U1PAD];
    const int tid = threadIdx.x, lane = tid & 63, w = tid >> 6;
    const int g = blockIdx.x;
    const int b = g / 125;
    const int n2base = (g - b*125) * 4;
    build_tab<512>(tab, tid);
    __syncthreads();
    // per-wave coalesced load (position order)
    {
        const cplx* yp = Y + (b*N2 + n2base + w)*N1;
        cplx* Uw = U[w];
#pragma unroll
        for(int t = 0; t < 8; ++t){
            int p = lane + 64*t;
            Uw[PX(p)] = yp[p];
        }
    }
    __syncthreads();
    cplx* Uw = U[w];
    wstage<8,  8,64,true,512>(Uw, tab, lane); __syncthreads();
    wstage<8, 64, 8,true,512>(Uw, tab, lane); __syncthreads();
    wstage<8,512, 1,true,512>(Uw, tab, lane); __syncthreads();
    // cooperative tiled store: 16 B segments over [n1][n2base..n2base+3]
    float* ob = out + b*NS + n2base;
    for(int i = tid; i < 512*4; i += 256){
        int n1 = i >> 2, ws = i & 3;
        ob[n1*500 + ws] = U[ws][PX(n1)].x;
    }
}

// ---------------------------------------------------------------------------
extern "C" void kernel_launch(void* const* d_in, const int* in_sizes, int n_in,
                              void* d_out, int out_size, void* d_ws, size_t ws_size,
                              hipStream_t stream) {
    const float* fm = (const float*)d_in[0];     // (4,500,64)
    const float* noise = (const float*)d_in[1];  // (4,256000)
    float* out = (float*)d_out;

    char* ws = (char*)d_ws;
    cplx*  Y     = (cplx*)ws;                    //  8,192,000 B
    float* resp2 = (float*)(ws + 8192000);       //  4,096,000 B
    float* mm    = (float*)(ws + 12288000);      //      1,024 B

    kT1<<<4, 256, 0, stream>>>(fm, mm);
    kT2<<<512, 256, 0, stream>>>(mm, resp2);
    kA<<<500, 256, 0, stream>>>(noise, Y);
    kB<<<512, 256, 0, stream>>>(Y, resp2);
    kC<<<500, 256, 0, stream>>>(Y, out);
}